// Round 10
// baseline (1143.916 us; speedup 1.0000x reference)
//
#include <hip/hip_runtime.h>

// HMM forward, B=64, T=1024, S=512, V=1024.
// Round 10: HYBRID MFMA + v_dot4_i32_i8. The broadcast-A matvec wastes 16x of
// MFMA M-rows (useful ~200 MACs/cyc/CU); VALU sdot4 does 512 MACs/cyc/CU with
// no waste and runs on a separate pipe, idle during the MFMA wall. Split each
// wave's 64 cols: tau0,tau1 (32 cols) via MFMA (Bf[2][8], 16 MFMA/wave ->
// wall halves to ~512 cyc/SIMD); tau2,tau3 (32 cols) via sdot4 (lanes l and
// l^32 each do one 256-MAC k-half of col wv*64+32+(l&31) from a column-packed
// u8 E copy in 64 VGPRs; shfl_xor(32) add routes the dot to owner lanes
// 32..63). Integer results bit-identical to the MFMA path. Ring = round 9
// (exp-domain, exact block max, 2 barriers, fused prep_scale).

constexpr int Bn = 64, Tn = 1024, Sn = 512;
#define L2E 1.44269504f

typedef int v4i __attribute__((ext_vector_type(4)));

#if __has_builtin(__builtin_amdgcn_update_dpp)
template <int CTRL>
__device__ __forceinline__ float dpp_fmax(float x) {
    int s = __builtin_bit_cast(int, x);
    int d = __builtin_amdgcn_update_dpp(s, s, CTRL, 0xf, 0xf, false);
    return fmaxf(x, __builtin_bit_cast(float, d));
}
// Full-wave max; result valid in lane 63 (no readlane broadcast).
__device__ __forceinline__ float wave_max64_l63(float x) {
    x = dpp_fmax<0x121>(x);   // row_ror:1
    x = dpp_fmax<0x122>(x);   // row_ror:2
    x = dpp_fmax<0x124>(x);   // row_ror:4
    x = dpp_fmax<0x128>(x);   // row_ror:8
    x = dpp_fmax<0x142>(x);   // row_bcast:15
    x = dpp_fmax<0x143>(x);   // row_bcast:31
    return x;
}
__device__ __forceinline__ float wave_max64(float x) {
    return __builtin_bit_cast(float,
        __builtin_amdgcn_readlane(
            __builtin_bit_cast(int, wave_max64_l63(x)), 63));
}
#else
__device__ __forceinline__ float wave_max64(float x) {
    #pragma unroll
    for (int off = 32; off; off >>= 1) x = fmaxf(x, __shfl_xor(x, off, 64));
    return x;
}
__device__ __forceinline__ float wave_max64_l63(float x) { return wave_max64(x); }
#endif

// Eq value for (row i, col c) -> B-fragment byte address:
// frag = (c>>4)*8 + (i>>6); lane = ((i>>4)&3)*16 + (c&15); byte = i&15
__device__ __forceinline__ int bfrag_addr(int i, int c) {
    return ((((c >> 4) * 8 + (i >> 6)) * 64) + ((i >> 4) & 3) * 16 + (c & 15)) * 16
           + (i & 15);
}

// Column-pack store for the VALU half (cols with (c&63)>=32):
// consuming thread tid = (c>>6)*64 + (i>>8)*32 + ((c&63)-32) holds byte (i&255).
__device__ __forceinline__ void eqv_store(unsigned char* EqV, int i, int c,
                                          unsigned char v) {
    int w = c & 63;
    if (w >= 32) {
        int slot = (c >> 6) * 64 + (i >> 8) * 32 + (w - 32);
        EqV[slot * 256 + (i & 255)] = v;
    }
}

// One block per row i: rowmax + quantize row to u8; scatter into B-frag layout
// (MFMA half) and column-pack layout (VALU half).
__global__ __launch_bounds__(256) void prep_rows(
    const float* __restrict__ trans, unsigned char* __restrict__ EqB,
    unsigned char* __restrict__ EqV, float* __restrict__ rowmax)
{
    const int i = blockIdx.x;
    const int j = threadIdx.x;
    const int lane = j & 63, wv = j >> 6;
    float t0 = trans[i * Sn + j];
    float t1 = trans[i * Sn + j + 256];
    float m = fmaxf(t0, t1);
    #pragma unroll
    for (int off = 32; off; off >>= 1) m = fmaxf(m, __shfl_xor(m, off, 64));
    __shared__ float rm[4];
    if (lane == 0) rm[wv] = m;
    __syncthreads();
    m = fmaxf(fmaxf(rm[0], rm[1]), fmaxf(rm[2], rm[3]));
    if (j == 0) rowmax[i] = m;
    int q0 = __float2int_rn(127.f * __expf(t0 - m));
    int q1 = __float2int_rn(127.f * __expf(t1 - m));
    EqB[bfrag_addr(i, j)] = (unsigned char)q0;
    EqB[bfrag_addr(i, j + 256)] = (unsigned char)q1;
    eqv_store(EqV, i, j, (unsigned char)q0);
    eqv_store(EqV, i, j + 256, (unsigned char)q1);
}

__global__ __launch_bounds__(512, 2) void hmm_fwd(
    const int* __restrict__ obs,          // [B, T]
    const float* __restrict__ emis,       // [V, S]
    const float* __restrict__ prior,      // [S]
    const v4i* __restrict__ EqB4,         // B-fragments, 16B per (frag,lane)
    const v4i* __restrict__ EqV4,         // column-pack, 256B per thread slot
    const float* __restrict__ rowmax,     // [S]
    float* __restrict__ out)              // [B]
{
    const int b = blockIdx.x;
    const int tid = threadIdx.x;          // state j owned by this thread
    const int lane = tid & 63, wv = tid >> 6;
    const int q = lane >> 4;

    __shared__ int obs_s[Tn + 1];
    __shared__ __align__(16) unsigned char Pq[Sn];
    __shared__ __align__(16) float redm[8];
    __shared__ float reds[8];

    int o0 = obs[b * Tn + tid];
    int o1 = obs[b * Tn + 512 + tid];
    obs_s[tid] = o0;
    obs_s[tid + 512] = o1;
    if (tid == 511) obs_s[Tn] = o1;       // pad: branch-free prefetch

    // MFMA B-fragments, tau in {0,1} only: cols wv*64+tau*16+(lane&15)
    v4i Bf[2][8];
    #pragma unroll
    for (int tau = 0; tau < 2; ++tau)
        #pragma unroll
        for (int kap = 0; kap < 8; ++kap)
            Bf[tau][kap] = EqB4[((wv * 4 + tau) * 8 + kap) * 64 + lane];

    // VALU E columns: this lane's (col, k-half) slice, 64 dwords
    v4i Ev[16];
    #pragma unroll
    for (int dq = 0; dq < 16; ++dq)
        Ev[dq] = EqV4[tid * 16 + dq];

    // ---- fused prep_scale: RM = max_i rowmax[i]; lrf_j = 127*exp(rowmax_j-RM)
    float rmj = rowmax[tid];
    {
        float r = wave_max64(rmj);
        if (lane == 0) redm[wv] = r;
    }
    __syncthreads();   // covers obs_s staging AND redm
    float RM;
    {
        float4 r0 = *(const float4*)&redm[0];
        float4 r1 = *(const float4*)&redm[4];
        RM = fmaxf(fmaxf(fmaxf(r0.x, r0.y), fmaxf(r0.z, r0.w)),
                   fmaxf(fmaxf(r1.x, r1.y), fmaxf(r1.z, r1.w)));
    }
    const float lrf = exp2f((rmj - RM) * L2E + 6.98868469f);  // log2(127)
    const float C = RM - 9.68837417f;                          // 2*ln(127)

    // alpha_0 in exp form: a_j = S + ln(wd_j), S = 0
    float wd = __expf(emis[obs_s[0] * Sn + tid] + prior[tid]);
    float lw = lrf * wd;
    float S = 0.f;
    float eC = emis[obs_s[1] * Sn + tid];   // raw emission for step 1

    for (int t = 1; t < Tn; ++t) {
        // ---- exact block max of wd: DPP in-wave (result in lane 63)
        float mx = wave_max64_l63(wd);
        if (lane == 63) redm[wv] = mx;
        int oN = obs_s[t + 1];                    // early LDS read (hidden)
        __syncthreads();                          // barrier 1
        float4 r0 = *(const float4*)&redm[0];
        float4 r1 = *(const float4*)&redm[4];
        float W = fmaxf(fmaxf(fmaxf(r0.x, r0.y), fmaxf(r0.z, r0.w)),
                        fmaxf(fmaxf(r1.x, r1.y), fmaxf(r1.z, r1.w)));

        float weC = __expf(eC);                   // TRANS, off-path

        // ---- quantize: q = round(lrf * wd / W)
        float rw = __builtin_amdgcn_rcpf(W);
        int gi = __float2int_rn(lw * rw);
        Pq[tid] = (unsigned char)gi;
        __syncthreads();                          // barrier 2

        eC = emis[oN * Sn + tid];                 // prefetch t+1 (hidden by dot)
        S += __logf(W) + C;                       // off-path scalar accumulate

        // ---- MFMA half (tau 0,1): A-frags quad-broadcast, 2 chained chains
        const unsigned char* Pbase = Pq + q * 16;
        v4i Af[8];
        #pragma unroll
        for (int kap = 0; kap < 8; ++kap)
            Af[kap] = *(const v4i*)(Pbase + kap * 64);
        v4i accM0 = {0, 0, 0, 0}, accM1 = {0, 0, 0, 0};
        #pragma unroll
        for (int kap = 0; kap < 8; ++kap) {
            accM0 = __builtin_amdgcn_mfma_i32_16x16x64_i8(Af[kap], Bf[0][kap],
                                                          accM0, 0, 0, 0);
            accM1 = __builtin_amdgcn_mfma_i32_16x16x64_i8(Af[kap], Bf[1][kap],
                                                          accM1, 0, 0, 0);
        }

        // ---- VALU half (tau 2,3): lane l does k-half (l>>5) of col
        //      wv*64+32+(l&31); 64 sdot4 in 4 independent chains.
        const v4i* Pv = (const v4i*)(Pq + (lane >> 5) * 256);
        int va = 0, vb = 0, vc = 0, vdd = 0;
        #pragma unroll
        for (int dq = 0; dq < 16; ++dq) {
            v4i pv = Pv[dq];
            va  = __builtin_amdgcn_sdot4(pv.x, Ev[dq].x, va,  false);
            vb  = __builtin_amdgcn_sdot4(pv.y, Ev[dq].y, vb,  false);
            vc  = __builtin_amdgcn_sdot4(pv.z, Ev[dq].z, vc,  false);
            vdd = __builtin_amdgcn_sdot4(pv.w, Ev[dq].w, vdd, false);
        }
        int vsum = (va + vb) + (vc + vdd);
        vsum += __shfl_xor(vsum, 32, 64);         // owner lanes 32..63 get full dot

        // ---- route: lanes 0..31 from MFMA select, lanes 32..63 from VALU
        int mres = (lane < 16) ? accM0.x : accM1.x;
        int idot = (lane < 32) ? mres : vsum;

        // ---- alpha update in exp form
        wd = weC * (float)idot;
        lw = lrf * wd;
    }

    // ---- out[b] = S + ln(sum_j wd_j)  via max-normalized sum
    float mw = wave_max64(wd);
    if (lane == 0) redm[wv] = mw;
    __syncthreads();
    float Wf = mw;
    #pragma unroll
    for (int w = 0; w < 8; ++w) Wf = fmaxf(Wf, redm[w]);

    float s = wd * __builtin_amdgcn_rcpf(Wf);
    #pragma unroll
    for (int off = 32; off; off >>= 1) s += __shfl_xor(s, off, 64);
    if (lane == 0) reds[wv] = s;
    __syncthreads();
    if (tid == 0) {
        float tot = 0.f;
        #pragma unroll
        for (int w = 0; w < 8; ++w) tot += reds[w];
        out[b] = S + __logf(Wf) + __logf(tot);
    }
}

extern "C" void kernel_launch(void* const* d_in, const int* in_sizes, int n_in,
                              void* d_out, int out_size, void* d_ws, size_t ws_size,
                              hipStream_t stream) {
    const int*   obs   = (const int*)d_in[0];
    const float* emis  = (const float*)d_in[1];
    const float* trans = (const float*)d_in[2];
    const float* prior = (const float*)d_in[3];
    float* out = (float*)d_out;

    unsigned char* EqB = (unsigned char*)d_ws;                // 256 KB
    unsigned char* EqV = EqB + Sn * Sn;                       // 128 KB
    float* rowmax = (float*)(EqV + 512 * 256);                // 2 KB

    prep_rows<<<Sn, 256, 0, stream>>>(trans, EqB, EqV, rowmax);
    hmm_fwd<<<Bn, Sn, 0, stream>>>(obs, emis, prior,
                                   (const v4i*)EqB, (const v4i*)EqV,
                                   rowmax, out);
}